// Round 10
// baseline (1291.899 us; speedup 1.0000x reference)
//
#include <hip/hip_runtime.h>

typedef _Float16 hf;
typedef _Float16 hf2 __attribute__((ext_vector_type(2)));
typedef _Float16 hf4 __attribute__((ext_vector_type(4)));
typedef _Float16 hf8 __attribute__((ext_vector_type(8)));
typedef float f4 __attribute__((ext_vector_type(4)));

#define NTH 512
// LDS map (bytes) — main kernel
#define ACT_OFF 0        // 32768: activations, packed 16x32 f16 tiles (m=s, k=f)
#define P_OFF   32768    // 8192: per-wave P tile
#define SC_OFF  40960    // 32768: H1 / Q,K,VT / OB / D / F1 / mean partials
#define SMEM_BYTES 73728

// d_ws layout
#define WSH_QKV 0          // [l][h] 12288 halves
#define WSH_WO  98304
#define WSH_FW1 131072
#define WSH_FW2 196608
#define WSH_CW2 262144
#define WSH_TOTAL 270336
#define CEMB_BYTE_OFF 540672
#define SP1_BYTE_OFF  2637824
#define TPH_SW1 0
#define TPH_TW1 131072
#define TPH_TW2 163840
#define TPH_MW1 196608
#define TPH_TOTAL 229376

__device__ __forceinline__ float dsilu(float x){ return x / (1.f + __expf(-x)); }
__device__ __forceinline__ float dtanh(float x){
  float xc = fminf(fmaxf(x, -10.f), 10.f);
  float e = __expf(2.f * xc);
  return (e - 1.f) / (e + 1.f);
}
__device__ __forceinline__ float fdot2f(hf2 a, hf2 b, float c){
#if __has_builtin(__builtin_amdgcn_fdot2)
  return __builtin_amdgcn_fdot2(a, b, c, false);
#else
  return c + (float)a[0]*(float)b[0] + (float)a[1]*(float)b[1];
#endif
}

// ---------------- prep 1: pack f32 weights -> f16 A-fragment tile order ----------------
__global__ void prep_pack(const float* __restrict__ wqkv, const float* __restrict__ wo,
                          const float* __restrict__ fw1, const float* __restrict__ fw2,
                          const float* __restrict__ cw2, hf* __restrict__ ws){
  int idx = blockIdx.x * 256 + threadIdx.x;
  if (idx >= WSH_TOTAL) return;
  float v;
  if (idx < WSH_WO){
    int u = idx; int lh = u / 12288; int l = lh >> 2, h = lh & 3;
    int r = u % 12288; int tl = r >> 9; int lane = (r >> 3) & 63; int j = r & 7;
    int q = lane >> 4, c = lane & 15;
    int tn = tl >> 2, tk = tl & 3;
    int k = tk*32 + q*8 + j, nloc = tn*16 + c;
    int gcol = (nloc >> 5)*128 + h*32 + (nloc & 31);
    v = wqkv[l*49152 + k*384 + gcol];
  } else if (idx < WSH_FW1){
    int u = idx - WSH_WO; int l = u >> 14; int r = u & 16383;
    int tl = r >> 9; int lane = (r >> 3) & 63; int j = r & 7;
    int q = lane >> 4, c = lane & 15;
    int tn = tl >> 2, tk = tl & 3;
    v = wo[l*16384 + (tk*32 + q*8 + j)*128 + tn*16 + c];
  } else if (idx < WSH_FW2){
    int u = idx - WSH_FW1; int lch = u >> 14; int l = lch >> 1, ch = lch & 1; int r = u & 16383;
    int tl = r >> 9; int lane = (r >> 3) & 63; int j = r & 7;
    int q = lane >> 4, c = lane & 15;
    int tn = tl >> 2, tk = tl & 3;
    v = fw1[l*32768 + (tk*32 + q*8 + j)*256 + ch*128 + tn*16 + c];
  } else if (idx < WSH_CW2){
    int u = idx - WSH_FW2; int lch = u >> 14; int l = lch >> 1, ch = lch & 1; int r = u & 16383;
    int tl = r >> 9; int lane = (r >> 3) & 63; int j = r & 7;
    int q = lane >> 4, c = lane & 15;
    int tn = tl >> 2, tk = tl & 3;
    v = fw2[l*32768 + (ch*128 + tk*32 + q*8 + j)*128 + tn*16 + c];
  } else {
    int u = idx - WSH_CW2;
    int tl = u >> 9; int lane = (u >> 3) & 63; int j = u & 7;
    int q = lane >> 4, c = lane & 15;
    int tn = tl >> 1, tk = tl & 1;
    v = cw2[(tk*32 + q*8 + j)*128 + tn*16 + c];
  }
  ws[idx] = (hf)v;
}

// ---------------- prep 2: pair-pack tail GEMV weights to f16 ----------------
__global__ void prep_pack2(const float* __restrict__ s_w1, const float* __restrict__ t_w1,
                           const float* __restrict__ t_w2, const float* __restrict__ mw_w1,
                           hf* __restrict__ sp1){
  int idx = blockIdx.x * 256 + threadIdx.x;
  if (idx >= TPH_TOTAL) return;
  float v;
  if (idx < TPH_TW1){
    int par = idx & 1, j = (idx >> 1) & 127, ip = (idx >> 8) & 127, k = idx >> 15;
    v = s_w1[k*33024 + (2 + 2*ip + par)*128 + j];
  } else if (idx < TPH_TW2){
    int u = idx - TPH_TW1;
    int par = u & 1, tc = (u >> 1) & 255, ip = u >> 9;
    v = t_w1[(2*ip + par)*256 + tc];
  } else if (idx < TPH_MW1){
    int u = idx - TPH_TW2;
    int par = u & 1, j = (u >> 1) & 127, ip = u >> 8;
    v = t_w2[(2*ip + par)*128 + j];
  } else {
    int u = idx - TPH_MW1;
    int par = u & 1, j = (u >> 1) & 127, ip = u >> 8;
    v = mw_w1[(2*ip + par)*128 + j];
  }
  sp1[idx] = (hf)v;
}

// ---------------- helpers ----------------
// 4 n-tiles x 2 s-tiles per wave; B from LDS (2 reads/tk), A from global (4 reads/tk)
template<int KT>
__device__ __forceinline__ void gemmC(f4 (&acc)[2][4], const hf* __restrict__ Ag, const hf* Bh,
                                      int nq, int sp2, int lane){
#pragma unroll
  for (int tk = 0; tk < KT; ++tk){
    hf8 b0 = *(const hf8*)(Bh + (((sp2*2    )*KT + tk) << 9) + lane*8);
    hf8 b1 = *(const hf8*)(Bh + (((sp2*2 + 1)*KT + tk) << 9) + lane*8);
#pragma unroll
    for (int jn = 0; jn < 4; ++jn){
      hf8 a = *(const hf8*)(Ag + (((nq*4 + jn)*KT + tk) << 9) + lane*8);
      acc[0][jn] = __builtin_amdgcn_mfma_f32_16x16x32_f16(a, b0, acc[0][jn], 0, 0, 0);
      acc[1][jn] = __builtin_amdgcn_mfma_f32_16x16x32_f16(a, b1, acc[1][jn], 0, 0, 0);
    }
  }
}

// same, but B fragments already in registers
template<int KT>
__device__ __forceinline__ void gemmCpreB(f4 (&acc)[2][4], const hf* __restrict__ Ag,
                                          const hf8 (&br)[2][KT], int nq, int lane){
#pragma unroll
  for (int tk = 0; tk < KT; ++tk){
#pragma unroll
    for (int jn = 0; jn < 4; ++jn){
      hf8 a = *(const hf8*)(Ag + (((nq*4 + jn)*KT + tk) << 9) + lane*8);
      acc[0][jn] = __builtin_amdgcn_mfma_f32_16x16x32_f16(a, br[0][tk], acc[0][jn], 0, 0, 0);
      acc[1][jn] = __builtin_amdgcn_mfma_f32_16x16x32_f16(a, br[1][tk], acc[1][jn], 0, 0, 0);
    }
  }
}

__device__ __forceinline__ void store_packed_b64(hf* dst, int KtilesOut, int ts, int ft,
                                                 f4 v, int q, int c){
  int tk = ft >> 1;
  int qp = ((ft & 1) << 1) + (q >> 1);
  int j0 = (q & 1) << 2;
  hf4 h; h[0] = (hf)v[0]; h[1] = (hf)v[1]; h[2] = (hf)v[2]; h[3] = (hf)v[3];
  *(hf4*)(dst + ((ts*KtilesOut + tk) << 9) + ((qp*16 + c) << 3) + j0) = h;
}

__device__ __forceinline__ void ln_pass(hf* A, const hf* Dh, const float* __restrict__ g,
                                        const float* __restrict__ bb, int t){
  int s = t >> 2, p = t & 3;
  float xr[4][8];
  int offs[4];
  float sum = 0.f, sq = 0.f;
#pragma unroll
  for (int tk = 0; tk < 4; ++tk){
    int off = (((s >> 4) * 4 + tk) << 9) + ((p * 16 + (s & 15)) << 3);
    offs[tk] = off;
    hf8 va = *(const hf8*)(A + off);
    hf8 vd = *(const hf8*)(Dh + off);
#pragma unroll
    for (int j = 0; j < 8; ++j){
      float x = (float)va[j] + (float)vd[j];
      xr[tk][j] = x; sum += x; sq += x * x;
    }
  }
  sum += __shfl_xor(sum, 1); sq += __shfl_xor(sq, 1);
  sum += __shfl_xor(sum, 2); sq += __shfl_xor(sq, 2);
  float mean = sum * (1.f/128.f);
  float rstd = rsqrtf(sq * (1.f/128.f) - mean*mean + 1e-5f);
#pragma unroll
  for (int tk = 0; tk < 4; ++tk){
    int f0 = tk*32 + p*8;
    f4 g0 = *(const f4*)(g + f0); f4 g1 = *(const f4*)(g + f0 + 4);
    f4 b0 = *(const f4*)(bb + f0); f4 b1 = *(const f4*)(bb + f0 + 4);
    hf8 y;
#pragma unroll
    for (int j = 0; j < 4; ++j){
      y[j]     = (hf)((xr[tk][j]     - mean) * rstd * g0[j] + b0[j]);
      y[j + 4] = (hf)((xr[tk][j + 4] - mean) * rstd * g1[j] + b1[j]);
    }
    *(hf8*)(A + offs[tk]) = y;
  }
}

// ---------------- main kernel: transformer only, one block per batch ----------------
__global__ __launch_bounds__(NTH, 4) void fused_fp(
    const float* __restrict__ cond,
    const float* __restrict__ c_w1, const float* __restrict__ c_b1, const float* __restrict__ c_b2,
    const float* __restrict__ bqkv_g, const float* __restrict__ bo_g,
    const float* __restrict__ ln1g_g, const float* __restrict__ ln1b_g,
    const float* __restrict__ fb1_g, const float* __restrict__ fb2_g,
    const float* __restrict__ ln2g_g, const float* __restrict__ ln2b_g,
    const hf* __restrict__ wsp, float* __restrict__ cemb)
{
  extern __shared__ char smem[];
  hf* ACTh = (hf*)(smem + ACT_OFF);
  hf* Ph   = (hf*)(smem + P_OFF);
  hf* SCh  = (hf*)(smem + SC_OFF);
  float* SCf = (float*)(smem + SC_OFF);
  hf* Qh  = SCh;
  hf* Kh  = (hf*)(smem + SC_OFF + 8192);
  hf* VTh = (hf*)(smem + SC_OFF + 16384);
  float* cst  = SCf + 4096;
  float* cw1s = SCf + 4864;

  const int b = blockIdx.x;
  const int t = threadIdx.x;
  const int w = t >> 6, lane = t & 63, q = lane >> 4, c = lane & 15;
  const int nq = w & 1, sp2 = w >> 1;

  // ===== cond staging =====
  for (int idx = t; idx < 768; idx += NTH) cst[idx] = cond[b * 768 + idx];
  if (t < 384) cw1s[t] = c_w1[t];
  if (t < 64)  cw1s[384 + t] = c_b1[t];
  __syncthreads();

  // cond MLP layer1 -> H1 packed in SC (Ktiles=2)
  for (int idx = t; idx < 8192; idx += NTH){
    int s = idx >> 6, jf = idx & 63;
    float a = cw1s[384 + jf];
#pragma unroll
    for (int cc = 0; cc < 6; ++cc) a += cst[s * 6 + cc] * cw1s[cc * 64 + jf];
    SCh[(((s >> 4)*2 + (jf >> 5)) << 9) + ((((jf & 31) >> 3)*16 + (s & 15)) << 3) + (jf & 7)] = (hf)dsilu(a);
  }
  __syncthreads();

  // cond MLP layer2 (MFMA) -> ACT
  {
    f4 acc[2][4];
#pragma unroll
    for (int i = 0; i < 2; ++i)
#pragma unroll
      for (int j = 0; j < 4; ++j){ f4 z = {0.f,0.f,0.f,0.f}; acc[i][j] = z; }
    gemmC<2>(acc, wsp + WSH_CW2, SCh, nq, sp2, lane);
#pragma unroll
    for (int jn = 0; jn < 4; ++jn){
      int ft = nq*4 + jn;
      f4 cb = *(const f4*)(c_b2 + ft*16 + q*4);
#pragma unroll
      for (int si = 0; si < 2; ++si){
        f4 v = acc[si][jn];
#pragma unroll
        for (int r = 0; r < 4; ++r) v[r] = dsilu(v[r] + cb[r]);
        store_packed_b64(ACTh, 4, sp2*2 + si, ft, v, q, c);
      }
    }
  }

  // ===== 2 transformer layers =====
  for (int l = 0; l < 2; ++l){
    f4 oacc[8];
#pragma unroll
    for (int i = 0; i < 8; ++i){ f4 z = {0.f,0.f,0.f,0.f}; oacc[i] = z; }
    hf8 bact[4];   // ACT B-frags for s-tile w: invariant across heads

    for (int h = 0; h < 4; ++h){
      __syncthreads();   // SC readers done before QKV epilogue writes; ACT final
      if (h == 0){
#pragma unroll
        for (int tk = 0; tk < 4; ++tk)
          bact[tk] = *(const hf8*)(ACTh + ((w*4 + tk) << 9) + lane*8);
      }
      // QKV GEMM: wave w computes all 6 n-tiles for s-tile w (B in regs)
      {
        const hf* Aq = wsp + WSH_QKV + (l*4 + h)*12288;
        f4 acc[6];
#pragma unroll
        for (int i = 0; i < 6; ++i){ f4 z = {0.f,0.f,0.f,0.f}; acc[i] = z; }
#pragma unroll
        for (int tk = 0; tk < 4; ++tk){
#pragma unroll
          for (int jn = 0; jn < 6; ++jn){
            hf8 a = *(const hf8*)(Aq + ((jn*4 + tk) << 9) + lane*8);
            acc[jn] = __builtin_amdgcn_mfma_f32_16x16x32_f16(a, bact[tk], acc[jn], 0, 0, 0);
          }
        }
#pragma unroll
        for (int ft = 0; ft < 6; ++ft){
          int sel = ft >> 1;
          f4 v = acc[ft];
          f4 bq = *(const f4*)(bqkv_g + l*384 + sel*128 + h*32 + (ft & 1)*16 + q*4);
#pragma unroll
          for (int r = 0; r < 4; ++r) v[r] += bq[r];
          if (sel == 0){
#pragma unroll
            for (int r = 0; r < 4; ++r) v[r] *= 0.17677669529663687f;
            store_packed_b64(Qh, 1, w, ft, v, q, c);
          } else if (sel == 1){
            store_packed_b64(Kh, 1, w, ft - 2, v, q, c);
          } else {
            int td = ft - 4;
            int qp = ((w & 1) << 1) + (c >> 3);
            hf* pb = VTh + ((td*4 + (w >> 1)) << 9) + (c & 7);
#pragma unroll
            for (int r = 0; r < 4; ++r) pb[(qp*16 + q*4 + r) << 3] = (hf)v[r];
          }
        }
      }
      __syncthreads();
      // scores + softmax (no max-sub; scores small) + P + AV (wave w owns q-tile w)
      {
        hf8 qf = *(const hf8*)(Qh + (w << 9) + lane*8);
        f4 sc[8];
#pragma unroll
        for (int kst = 0; kst < 8; ++kst){
          hf8 kv = *(const hf8*)(Kh + (kst << 9) + lane*8);
          f4 z = {0.f,0.f,0.f,0.f};
          sc[kst] = __builtin_amdgcn_mfma_f32_16x16x32_f16(kv, qf, z, 0, 0, 0);
        }
        float ls = 0.f;
#pragma unroll
        for (int kst = 0; kst < 8; ++kst)
#pragma unroll
          for (int r = 0; r < 4; ++r){
            float e = __expf(sc[kst][r]);
            sc[kst][r] = e; ls += e;
          }
        ls += __shfl_xor(ls, 16);
        ls += __shfl_xor(ls, 32);
        float rl = 1.f / ls;
        hf* Pw = Ph + (w << 9);
#pragma unroll
        for (int ks = 0; ks < 4; ++ks){
#pragma unroll
          for (int h2 = 0; h2 < 2; ++h2){
            int kst = 2*ks + h2;
            int qp = h2*2 + (q >> 1);
            int j0 = (q & 1) << 2;
            hf4 pv;
#pragma unroll
            for (int r = 0; r < 4; ++r) pv[r] = (hf)(sc[kst][r] * rl);
            *(hf4*)(Pw + qp*128 + c*8 + j0) = pv;
          }
          hf8 bp = *(const hf8*)(Pw + lane*8);
          hf8 a0 = *(const hf8*)(VTh + ((     ks) << 9) + lane*8);
          hf8 a1 = *(const hf8*)(VTh + ((4 +  ks) << 9) + lane*8);
          oacc[2*h]     = __builtin_amdgcn_mfma_f32_16x16x32_f16(a0, bp, oacc[2*h],     0, 0, 0);
          oacc[2*h + 1] = __builtin_amdgcn_mfma_f32_16x16x32_f16(a1, bp, oacc[2*h + 1], 0, 0, 0);
        }
      }
    } // heads

    __syncthreads();
#pragma unroll
    for (int ft = 0; ft < 8; ++ft) store_packed_b64(SCh, 4, w, ft, oacc[ft], q, c);
    __syncthreads();

    // WO projection (4n x 2s)
    {
      f4 acc[2][4];
#pragma unroll
      for (int i = 0; i < 2; ++i)
#pragma unroll
        for (int j = 0; j < 4; ++j){ f4 z = {0.f,0.f,0.f,0.f}; acc[i][j] = z; }
      gemmC<4>(acc, wsp + WSH_WO + l*16384, SCh, nq, sp2, lane);
      __syncthreads();
#pragma unroll
      for (int jn = 0; jn < 4; ++jn){
        int ft = nq*4 + jn;
        f4 bo = *(const f4*)(bo_g + l*128 + ft*16 + q*4);
#pragma unroll
        for (int si = 0; si < 2; ++si){
          f4 v = acc[si][jn];
#pragma unroll
          for (int r = 0; r < 4; ++r) v[r] += bo[r];
          store_packed_b64(SCh, 4, sp2*2 + si, ft, v, q, c);
        }
      }
    }
    __syncthreads();
    ln_pass(ACTh, SCh, ln1g_g + l*128, ln1b_g + l*128, t);
    __syncthreads();

    // FFN (4n x 2s), ACT B-frags hoisted across both chunks
    {
      hf8 bffn[2][4];
#pragma unroll
      for (int si = 0; si < 2; ++si)
#pragma unroll
        for (int tk = 0; tk < 4; ++tk)
          bffn[si][tk] = *(const hf8*)(ACTh + (((sp2*2 + si)*4 + tk) << 9) + lane*8);
      f4 facc[2][4];
#pragma unroll
      for (int i = 0; i < 2; ++i)
#pragma unroll
        for (int j = 0; j < 4; ++j){ f4 z = {0.f,0.f,0.f,0.f}; facc[i][j] = z; }
      for (int ch = 0; ch < 2; ++ch){
        f4 acc[2][4];
#pragma unroll
        for (int i = 0; i < 2; ++i)
#pragma unroll
          for (int j = 0; j < 4; ++j){ f4 z = {0.f,0.f,0.f,0.f}; acc[i][j] = z; }
        gemmCpreB<4>(acc, wsp + WSH_FW1 + (l*2 + ch)*16384, bffn, nq, lane);
#pragma unroll
        for (int jn = 0; jn < 4; ++jn){
          int ft = nq*4 + jn;
          f4 fb = *(const f4*)(fb1_g + l*256 + ch*128 + ft*16 + q*4);
#pragma unroll
          for (int si = 0; si < 2; ++si){
            f4 v = acc[si][jn];
#pragma unroll
            for (int r = 0; r < 4; ++r) v[r] = fmaxf(v[r] + fb[r], 0.f);
            store_packed_b64(SCh, 4, sp2*2 + si, ft, v, q, c);
          }
        }
        __syncthreads();
        gemmC<4>(facc, wsp + WSH_FW2 + (l*2 + ch)*16384, SCh, nq, sp2, lane);
        __syncthreads();
      }
#pragma unroll
      for (int jn = 0; jn < 4; ++jn){
        int ft = nq*4 + jn;
        f4 fb = *(const f4*)(fb2_g + l*128 + ft*16 + q*4);
#pragma unroll
        for (int si = 0; si < 2; ++si){
          f4 v = facc[si][jn];
#pragma unroll
          for (int r = 0; r < 4; ++r) v[r] += fb[r];
          store_packed_b64(SCh, 4, sp2*2 + si, ft, v, q, c);
        }
      }
    }
    __syncthreads();
    ln_pass(ACTh, SCh, ln2g_g + l*128, ln2b_g + l*128, t);
    __syncthreads();
  } // layers

  // ===== cond_emb mean over s -> cemb[b] (global) =====
  {
    int o = t & 15;
    float fs[8];
#pragma unroll
    for (int j = 0; j < 8; ++j) fs[j] = 0.f;
#pragma unroll
    for (int u = 0; u < 4; ++u){
      int s = (t >> 4)*4 + u;
      hf8 v = *(const hf8*)(ACTh + (((s >> 4)*4 + (o >> 2)) << 9) + (((o & 3)*16 + (s & 15)) << 3));
#pragma unroll
      for (int j = 0; j < 8; ++j) fs[j] += (float)v[j];
    }
#pragma unroll
    for (int j = 0; j < 8; ++j){
      fs[j] += __shfl_xor(fs[j], 16);
      fs[j] += __shfl_xor(fs[j], 32);
    }
    if (lane < 16){
      f4 v0, v1;
#pragma unroll
      for (int j = 0; j < 4; ++j){ v0[j] = fs[j]; v1[j] = fs[j+4]; }
      *(f4*)(SCf + w*128 + o*8)     = v0;
      *(f4*)(SCf + w*128 + o*8 + 4) = v1;
    }
  }
  __syncthreads();
  if (t < 128){
    float a = 0.f;
#pragma unroll
    for (int wv = 0; wv < 8; ++wv) a += SCf[wv*128 + t];
    cemb[b*128 + t] = a * (1.f/128.f);
  }
}

// ---------------- tail kernel: one block per batch, 256 threads ----------------
__global__ __launch_bounds__(256, 8) void tail_k(
    const float* __restrict__ x, const int* __restrict__ tstep, const float* __restrict__ cemb,
    const float* __restrict__ t_b1, const float* __restrict__ t_b2,
    const float* __restrict__ mw_b1,
    const float* __restrict__ mw_w2, const float* __restrict__ mw_b2,
    const float* __restrict__ s_w1, const float* __restrict__ s_b1,
    const float* __restrict__ s_w2, const float* __restrict__ s_b2,
    const hf* __restrict__ sp1, float* __restrict__ out)
{
  __shared__ float sw01[1024], sw2[1024];
  __shared__ float cvec[512];
  __shared__ float scr[1024];
  __shared__ float mwh[128], mwls[4];
  __shared__ hf te_h[128], th_h[256], comb_h[256];
  const int b = blockIdx.x;
  const int t = threadIdx.x;

  for (int i = t; i < 1024; i += 256){
    int row = i >> 9, k = (i >> 7) & 3, j = i & 127;
    sw01[i] = s_w1[k*33024 + row*128 + j];
    sw2[i]  = s_w2[i];
  }
  if (t < 128){
    int i = t & 63;
    float f = __expf(-logf(10000.f) * (float)i * (1.f/64.f));
    float a = (float)tstep[b] * f;
    te_h[t] = (hf)((t < 64) ? cosf(a) : sinf(a));
    comb_h[128 + t] = (hf)cemb[b*128 + t];
  }
  __syncthreads();

  {
    const hf* tp1 = sp1 + TPH_TW1;
    float a = t_b1[t];
#pragma unroll 8
    for (int ii = 0; ii < 64; ++ii){
      hf2 wp = *(const hf2*)(tp1 + ii*512 + 2*t);
      hf2 tp = *(const hf2*)(te_h + 2*ii);
      a = fdot2f(tp, wp, a);
    }
    th_h[t] = (hf)dsilu(a);
  }
  __syncthreads();

  {
    const hf* tp2 = sp1 + TPH_TW2;
    int ih = t >> 7, j = t & 127;
    float a = ih ? 0.f : t_b2[j];
#pragma unroll 8
    for (int ii = 0; ii < 64; ++ii){
      hf2 wp = *(const hf2*)(tp2 + (ih*64 + ii)*256 + 2*j);
      hf2 tp = *(const hf2*)(th_h + ih*128 + 2*ii);
      a = fdot2f(tp, wp, a);
    }
    scr[t] = a;
  }
  __syncthreads();
  if (t < 128) comb_h[t] = (hf)(scr[t] + scr[128 + t]);
  __syncthreads();

  {
    const hf* swp = sp1 + TPH_SW1;
    int ih = t >> 7, k = (t >> 5) & 3, j4 = t & 31;
    f4 a = {0.f, 0.f, 0.f, 0.f};
    const hf* wp = swp + ((k*128 + ih*64)*128 + j4*4)*2;
#pragma unroll 4
    for (int ii = 0; ii < 64; ++ii){
      hf8 wv = *(const hf8*)(wp + ii*256);
      hf2 cb = *(const hf2*)(comb_h + ih*128 + 2*ii);
      hf2 w01; w01[0] = wv[0]; w01[1] = wv[1];
      hf2 w23; w23[0] = wv[2]; w23[1] = wv[3];
      hf2 w45; w45[0] = wv[4]; w45[1] = wv[5];
      hf2 w67; w67[0] = wv[6]; w67[1] = wv[7];
      a[0] = fdot2f(cb, w01, a[0]);
      a[1] = fdot2f(cb, w23, a[1]);
      a[2] = fdot2f(cb, w45, a[2]);
      a[3] = fdot2f(cb, w67, a[3]);
    }
    ((f4*)scr)[ih*128 + k*32 + j4] = a;
  }
  __syncthreads();

  if (t < 128){
    f4 r0 = ((f4*)scr)[t];
    f4 r1 = ((f4*)scr)[128 + t];
    int k = t >> 5, j4 = t & 31;
    f4 sb = *(const f4*)(s_b1 + k*128 + j4*4);
    f4 r; r[0] = r0[0]+r1[0]+sb[0]; r[1] = r0[1]+r1[1]+sb[1];
    r[2] = r0[2]+r1[2]+sb[2]; r[3] = r0[3]+r1[3]+sb[3];
    ((f4*)cvec)[t] = r;
  } else {
    const hf* mp1 = sp1 + TPH_MW1;
    int j = t - 128;
    float a = mw_b1[j];
#pragma unroll 8
    for (int ii = 0; ii < 128; ++ii){
      hf2 wp = *(const hf2*)(mp1 + ii*256 + 2*j);
      hf2 cp = *(const hf2*)(comb_h + 2*ii);
      a = fdot2f(cp, wp, a);
    }
    mwh[j] = dsilu(a);
  }
  __syncthreads();

  if (t < 64){
    int cc = t & 3, j0 = t >> 2;
    float a = 0.f;
#pragma unroll
    for (int i = 0; i < 8; ++i){
      int j = j0 + 16*i;
      a += mwh[j] * mw_w2[j*4 + cc];
    }
    a += __shfl_xor(a, 4);
    a += __shfl_xor(a, 8);
    a += __shfl_xor(a, 16);
    a += __shfl_xor(a, 32);
    if (t < 4) mwls[t] = a + mw_b2[t];
  }
#pragma unroll
  for (int u = 0; u < 2; ++u){
    int o = t + u*256, k = o >> 7, s = o & 127;
    float x0 = x[b*256 + s];
    float x1 = x[b*256 + 128 + s];
    float a0 = 0.f, a1 = 0.f;
    const f4* cvp = (const f4*)cvec + k*32;
    const f4* w0p = (const f4*)sw01 + k*32;
    const f4* w1p = (const f4*)sw01 + 128 + k*32;
    const f4* s2p = (const f4*)sw2 + k*64;
#pragma unroll 2
    for (int j4 = 0; j4 < 32; ++j4){
      f4 cv = cvp[j4], w0 = w0p[j4], w1 = w1p[j4];
      f4 s20 = s2p[2*j4], s21 = s2p[2*j4 + 1];
      float h0 = dtanh(cv[0] + x0*w0[0] + x1*w1[0]);
      float h1 = dtanh(cv[1] + x0*w0[1] + x1*w1[1]);
      float h2 = dtanh(cv[2] + x0*w0[2] + x1*w1[2]);
      float h3 = dtanh(cv[3] + x0*w0[3] + x1*w1[3]);
      a0 += h0*s20[0] + h1*s20[2] + h2*s21[0] + h3*s21[2];
      a1 += h0*s20[1] + h1*s20[3] + h2*s21[1] + h3*s21[3];
    }
    scr[k*256 + s]       = a0 + s_b2[2*k];
    scr[k*256 + 128 + s] = a1 + s_b2[2*k + 1];
  }
  __syncthreads();

  {
    int row = t >> 7, s = t & 127;
    float l0 = mwls[0], l1 = mwls[1], l2 = mwls[2], l3 = mwls[3];
    float mx = fmaxf(fmaxf(l0, l1), fmaxf(l2, l3));
    float e0 = __expf(l0 - mx), e1 = __expf(l1 - mx), e2 = __expf(l2 - mx), e3 = __expf(l3 - mx);
    float rs = 1.f / (e0 + e1 + e2 + e3);
    float a = e0*scr[0*256 + row*128 + s] + e1*scr[1*256 + row*128 + s]
            + e2*scr[2*256 + row*128 + s] + e3*scr[3*256 + row*128 + s];
    out[b*256 + row*128 + s] = a * rs;
  }
}

extern "C" void kernel_launch(void* const* d_in, const int* in_sizes, int n_in,
                              void* d_out, int out_size, void* d_ws, size_t ws_size,
                              hipStream_t stream){
  (void)n_in; (void)ws_size; (void)out_size;
  hipFuncSetAttribute((const void*)fused_fp, hipFuncAttributeMaxDynamicSharedMemorySize, SMEM_BYTES);
  int B = in_sizes[1];
  hf* wsp = (hf*)d_ws;
  float* cemb = (float*)((char*)d_ws + CEMB_BYTE_OFF);
  hf* sp1 = (hf*)((char*)d_ws + SP1_BYTE_OFF);
  prep_pack<<<dim3((WSH_TOTAL + 255) / 256), dim3(256), 0, stream>>>(
      (const float*)d_in[11], (const float*)d_in[13], (const float*)d_in[17],
      (const float*)d_in[19], (const float*)d_in[9], wsp);
  prep_pack2<<<dim3((TPH_TOTAL + 255) / 256), dim3(256), 0, stream>>>(
      (const float*)d_in[27], (const float*)d_in[3], (const float*)d_in[5],
      (const float*)d_in[23], sp1);
  fused_fp<<<dim3(B), dim3(NTH), SMEM_BYTES, stream>>>(
      (const float*)d_in[2],
      (const float*)d_in[7], (const float*)d_in[8], (const float*)d_in[10],
      (const float*)d_in[12], (const float*)d_in[14],
      (const float*)d_in[15], (const float*)d_in[16],
      (const float*)d_in[18], (const float*)d_in[20],
      (const float*)d_in[21], (const float*)d_in[22],
      wsp, cemb);
  tail_k<<<dim3(B), dim3(256), 0, stream>>>(
      (const float*)d_in[0], (const int*)d_in[1], cemb,
      (const float*)d_in[4], (const float*)d_in[6],
      (const float*)d_in[24],
      (const float*)d_in[25], (const float*)d_in[26],
      (const float*)d_in[27], (const float*)d_in[28], (const float*)d_in[29], (const float*)d_in[30],
      sp1, (float*)d_out);
}

// Round 11
// 973.379 us; speedup vs baseline: 1.3272x; 1.3272x over previous
//
#include <hip/hip_runtime.h>

typedef _Float16 hf;
typedef _Float16 hf2 __attribute__((ext_vector_type(2)));
typedef _Float16 hf4 __attribute__((ext_vector_type(4)));
typedef _Float16 hf8 __attribute__((ext_vector_type(8)));
typedef float f4 __attribute__((ext_vector_type(4)));

#define NTH 512
// LDS map (bytes) — main kernel
#define ACT_OFF 0        // 32768: activations, packed 16x32 f16 tiles (m=s, k=f)
#define P_OFF   32768    // 8192: per-wave P tile
#define SC_OFF  40960    // 32768: H1 / Q,K,VT / OB / D / F1 / mean partials
#define SMEM_BYTES 73728

// d_ws layout
#define WSH_QKV 0          // [l][h] 12288 halves
#define WSH_WO  98304
#define WSH_FW1 131072
#define WSH_FW2 196608
#define WSH_CW2 262144
#define WSH_TOTAL 270336
#define CEMB_BYTE_OFF 540672
#define SP1_BYTE_OFF  2637824
#define TPH_SW1 0
#define TPH_TW1 131072
#define TPH_TW2 163840
#define TPH_MW1 196608
#define TPH_TOTAL 229376

__device__ __forceinline__ float dsilu(float x){ return x / (1.f + __expf(-x)); }
__device__ __forceinline__ float dtanh(float x){
  float xc = fminf(fmaxf(x, -10.f), 10.f);
  float e = __expf(2.f * xc);
#if __has_builtin(__builtin_amdgcn_rcpf)
  return 1.f - 2.f * __builtin_amdgcn_rcpf(e + 1.f);
#else
  return (e - 1.f) / (e + 1.f);
#endif
}
__device__ __forceinline__ float fdot2f(hf2 a, hf2 b, float c){
#if __has_builtin(__builtin_amdgcn_fdot2)
  return __builtin_amdgcn_fdot2(a, b, c, false);
#else
  return c + (float)a[0]*(float)b[0] + (float)a[1]*(float)b[1];
#endif
}

// ---------------- merged prep: MFMA-order weights + pair-packed tail weights ----------------
__global__ void prep_all(const float* __restrict__ wqkv, const float* __restrict__ wo,
                         const float* __restrict__ fw1, const float* __restrict__ fw2,
                         const float* __restrict__ cw2,
                         const float* __restrict__ s_w1, const float* __restrict__ t_w1,
                         const float* __restrict__ t_w2, const float* __restrict__ mw_w1,
                         hf* __restrict__ ws, hf* __restrict__ sp1){
  int idx = blockIdx.x * 256 + threadIdx.x;
  if (idx < WSH_TOTAL){
    float v;
    if (idx < WSH_WO){
      int u = idx; int lh = u / 12288; int l = lh >> 2, h = lh & 3;
      int r = u % 12288; int tl = r >> 9; int lane = (r >> 3) & 63; int j = r & 7;
      int q = lane >> 4, c = lane & 15;
      int tn = tl >> 2, tk = tl & 3;
      int k = tk*32 + q*8 + j, nloc = tn*16 + c;
      int gcol = (nloc >> 5)*128 + h*32 + (nloc & 31);
      v = wqkv[l*49152 + k*384 + gcol];
    } else if (idx < WSH_FW1){
      int u = idx - WSH_WO; int l = u >> 14; int r = u & 16383;
      int tl = r >> 9; int lane = (r >> 3) & 63; int j = r & 7;
      int q = lane >> 4, c = lane & 15;
      int tn = tl >> 2, tk = tl & 3;
      v = wo[l*16384 + (tk*32 + q*8 + j)*128 + tn*16 + c];
    } else if (idx < WSH_FW2){
      int u = idx - WSH_FW1; int lch = u >> 14; int l = lch >> 1, ch = lch & 1; int r = u & 16383;
      int tl = r >> 9; int lane = (r >> 3) & 63; int j = r & 7;
      int q = lane >> 4, c = lane & 15;
      int tn = tl >> 2, tk = tl & 3;
      v = fw1[l*32768 + (tk*32 + q*8 + j)*256 + ch*128 + tn*16 + c];
    } else if (idx < WSH_CW2){
      int u = idx - WSH_FW2; int lch = u >> 14; int l = lch >> 1, ch = lch & 1; int r = u & 16383;
      int tl = r >> 9; int lane = (r >> 3) & 63; int j = r & 7;
      int q = lane >> 4, c = lane & 15;
      int tn = tl >> 2, tk = tl & 3;
      v = fw2[l*32768 + (ch*128 + tk*32 + q*8 + j)*128 + tn*16 + c];
    } else {
      int u = idx - WSH_CW2;
      int tl = u >> 9; int lane = (u >> 3) & 63; int j = u & 7;
      int q = lane >> 4, c = lane & 15;
      int tn = tl >> 1, tk = tl & 1;
      v = cw2[(tk*32 + q*8 + j)*128 + tn*16 + c];
    }
    ws[idx] = (hf)v;
  } else {
    int ix = idx - WSH_TOTAL;
    if (ix >= TPH_TOTAL) return;
    float v;
    if (ix < TPH_TW1){
      int par = ix & 1, j = (ix >> 1) & 127, ip = (ix >> 8) & 127, k = ix >> 15;
      v = s_w1[k*33024 + (2 + 2*ip + par)*128 + j];
    } else if (ix < TPH_TW2){
      int u = ix - TPH_TW1;
      int par = u & 1, tc = (u >> 1) & 255, ip = u >> 9;
      v = t_w1[(2*ip + par)*256 + tc];
    } else if (ix < TPH_MW1){
      int u = ix - TPH_TW2;
      int par = u & 1, j = (u >> 1) & 127, ip = u >> 8;
      v = t_w2[(2*ip + par)*128 + j];
    } else {
      int u = ix - TPH_MW1;
      int par = u & 1, j = (u >> 1) & 127, ip = u >> 8;
      v = mw_w1[(2*ip + par)*128 + j];
    }
    sp1[ix] = (hf)v;
  }
}

// ---------------- helpers ----------------
template<int KT>
__device__ __forceinline__ void loadA2(hf8 (&ar)[2][KT], const hf* __restrict__ Ag, int npair, int lane){
#pragma unroll
  for (int jn = 0; jn < 2; ++jn)
#pragma unroll
    for (int tk = 0; tk < KT; ++tk)
      ar[jn][tk] = *(const hf8*)(Ag + (((2*npair + jn)*KT + tk) << 9) + lane*8);
}

template<int KT>
__device__ __forceinline__ void gemmBpre(f4 (&acc)[4][2], const hf8 (&ar)[2][KT], const hf* Bh,
                                         int shalf, int lane){
#pragma unroll
  for (int tk = 0; tk < KT; ++tk){
#pragma unroll
    for (int si = 0; si < 4; ++si){
      hf8 b = *(const hf8*)(Bh + (((shalf*4 + si)*KT + tk) << 9) + lane*8);
      acc[si][0] = __builtin_amdgcn_mfma_f32_16x16x32_f16(ar[0][tk], b, acc[si][0], 0, 0, 0);
      acc[si][1] = __builtin_amdgcn_mfma_f32_16x16x32_f16(ar[1][tk], b, acc[si][1], 0, 0, 0);
    }
  }
}

__device__ __forceinline__ void store_packed_b64(hf* dst, int KtilesOut, int ts, int ft,
                                                 f4 v, int q, int c){
  int tk = ft >> 1;
  int qp = ((ft & 1) << 1) + (q >> 1);
  int j0 = (q & 1) << 2;
  hf4 h; h[0] = (hf)v[0]; h[1] = (hf)v[1]; h[2] = (hf)v[2]; h[3] = (hf)v[3];
  *(hf4*)(dst + ((ts*KtilesOut + tk) << 9) + ((qp*16 + c) << 3) + j0) = h;
}

// LN in fragment layout: wave w owns s-tile w; lane reads its own lane*8 slot per k-tile
// (conflict-free, same pattern as GEMM B-frag reads). f = tk*32 + qp*8 + j.
// Reduce over f across lanes {c, c+16, c+32, c+48} via shfl_xor 16/32.
__device__ __forceinline__ void ln_pass(hf* A, const hf* Dh, const float* __restrict__ g,
                                        const float* __restrict__ bb, int t){
  int w = t >> 6, lane = t & 63, qp = lane >> 4;
  float xr[4][8];
  int offs[4];
  float sum = 0.f, sq = 0.f;
#pragma unroll
  for (int tk = 0; tk < 4; ++tk){
    int off = ((w*4 + tk) << 9) + lane*8;
    offs[tk] = off;
    hf8 va = *(const hf8*)(A + off);
    hf8 vd = *(const hf8*)(Dh + off);
#pragma unroll
    for (int j = 0; j < 8; ++j){
      float x = (float)va[j] + (float)vd[j];
      xr[tk][j] = x; sum += x; sq += x * x;
    }
  }
  sum += __shfl_xor(sum, 16); sq += __shfl_xor(sq, 16);
  sum += __shfl_xor(sum, 32); sq += __shfl_xor(sq, 32);
  float mean = sum * (1.f/128.f);
  float rstd = rsqrtf(sq * (1.f/128.f) - mean*mean + 1e-5f);
#pragma unroll
  for (int tk = 0; tk < 4; ++tk){
    int f0 = tk*32 + qp*8;
    f4 g0 = *(const f4*)(g + f0); f4 g1 = *(const f4*)(g + f0 + 4);
    f4 b0 = *(const f4*)(bb + f0); f4 b1 = *(const f4*)(bb + f0 + 4);
    hf8 y;
#pragma unroll
    for (int j = 0; j < 4; ++j){
      y[j]     = (hf)((xr[tk][j]     - mean) * rstd * g0[j] + b0[j]);
      y[j + 4] = (hf)((xr[tk][j + 4] - mean) * rstd * g1[j] + b1[j]);
    }
    *(hf8*)(A + offs[tk]) = y;
  }
}

// ---------------- main kernel: transformer only, one block per batch ----------------
__global__ __launch_bounds__(NTH, 4) void fused_fp(
    const float* __restrict__ cond,
    const float* __restrict__ c_w1, const float* __restrict__ c_b1, const float* __restrict__ c_b2,
    const float* __restrict__ bqkv_g, const float* __restrict__ bo_g,
    const float* __restrict__ ln1g_g, const float* __restrict__ ln1b_g,
    const float* __restrict__ fb1_g, const float* __restrict__ fb2_g,
    const float* __restrict__ ln2g_g, const float* __restrict__ ln2b_g,
    const hf* __restrict__ wsp, float* __restrict__ cemb)
{
  extern __shared__ char smem[];
  hf* ACTh = (hf*)(smem + ACT_OFF);
  hf* Ph   = (hf*)(smem + P_OFF);
  hf* SCh  = (hf*)(smem + SC_OFF);
  float* SCf = (float*)(smem + SC_OFF);
  hf* Qh  = SCh;
  hf* Kh  = (hf*)(smem + SC_OFF + 8192);
  hf* VTh = (hf*)(smem + SC_OFF + 16384);
  float* cst  = SCf + 4096;
  float* cw1s = SCf + 4864;

  const int b = blockIdx.x;
  const int t = threadIdx.x;
  const int w = t >> 6, lane = t & 63, q = lane >> 4, c = lane & 15;
  const int sp = w & 3, np = w >> 2;
  const int npair = w & 3, shalf = w >> 2;

  // ===== cond staging =====
  for (int idx = t; idx < 768; idx += NTH) cst[idx] = cond[b * 768 + idx];
  if (t < 384) cw1s[t] = c_w1[t];
  if (t < 64)  cw1s[384 + t] = c_b1[t];
  __syncthreads();

  // cond MLP layer1 -> H1 packed in SC (Ktiles=2)
  for (int idx = t; idx < 8192; idx += NTH){
    int s = idx >> 6, jf = idx & 63;
    float a = cw1s[384 + jf];
#pragma unroll
    for (int cc = 0; cc < 6; ++cc) a += cst[s * 6 + cc] * cw1s[cc * 64 + jf];
    SCh[(((s >> 4)*2 + (jf >> 5)) << 9) + ((((jf & 31) >> 3)*16 + (s & 15)) << 3) + (jf & 7)] = (hf)dsilu(a);
  }
  // prefetch cond-L2 A fragments (overlaps the barrier)
  {
    hf8 acw[2][2];
    loadA2<2>(acw, wsp + WSH_CW2, npair, lane);
    __syncthreads();
    f4 acc[4][2];
#pragma unroll
    for (int i = 0; i < 4; ++i)
#pragma unroll
      for (int j = 0; j < 2; ++j){ f4 z = {0.f,0.f,0.f,0.f}; acc[i][j] = z; }
    gemmBpre<2>(acc, acw, SCh, shalf, lane);
    f4 cb0 = *(const f4*)(c_b2 + (2*npair    )*16 + q*4);
    f4 cb1 = *(const f4*)(c_b2 + (2*npair + 1)*16 + q*4);
#pragma unroll
    for (int si = 0; si < 4; ++si)
#pragma unroll
      for (int jn = 0; jn < 2; ++jn){
        f4 v = acc[si][jn];
        f4 cb = jn ? cb1 : cb0;
#pragma unroll
        for (int r = 0; r < 4; ++r) v[r] = dsilu(v[r] + cb[r]);
        store_packed_b64(ACTh, 4, shalf*4 + si, 2*npair + jn, v, q, c);
      }
  }

  // ===== 2 transformer layers =====
  for (int l = 0; l < 2; ++l){
    f4 oacc[8];
#pragma unroll
    for (int i = 0; i < 8; ++i){ f4 z = {0.f,0.f,0.f,0.f}; oacc[i] = z; }

    for (int h = 0; h < 4; ++h){
      // prefetch QKV A fragments before the barrier
      hf8 aq[3][4];
      {
        const hf* Aq = wsp + WSH_QKV + (l*4 + h)*12288;
#pragma unroll
        for (int jn = 0; jn < 3; ++jn)
#pragma unroll
          for (int tk = 0; tk < 4; ++tk)
            aq[jn][tk] = *(const hf8*)(Aq + (((np*3 + jn)*4 + tk) << 9) + lane*8);
      }
      __syncthreads();   // SC readers done before QKV epilogue writes
      {
        f4 acc[2][3];
#pragma unroll
        for (int i = 0; i < 2; ++i)
#pragma unroll
          for (int j = 0; j < 3; ++j){ f4 z = {0.f,0.f,0.f,0.f}; acc[i][j] = z; }
#pragma unroll
        for (int tk = 0; tk < 4; ++tk){
          hf8 b0 = *(const hf8*)(ACTh + (((2*sp  )*4 + tk) << 9) + lane*8);
          hf8 b1 = *(const hf8*)(ACTh + (((2*sp+1)*4 + tk) << 9) + lane*8);
#pragma unroll
          for (int jn = 0; jn < 3; ++jn){
            acc[0][jn] = __builtin_amdgcn_mfma_f32_16x16x32_f16(aq[jn][tk], b0, acc[0][jn], 0, 0, 0);
            acc[1][jn] = __builtin_amdgcn_mfma_f32_16x16x32_f16(aq[jn][tk], b1, acc[1][jn], 0, 0, 0);
          }
        }
#pragma unroll
        for (int si = 0; si < 2; ++si)
#pragma unroll
          for (int jn = 0; jn < 3; ++jn){
            int ft = np*3 + jn, ts = 2*sp + si;
            int sel = ft >> 1;
            f4 v = acc[si][jn];
            f4 bq = *(const f4*)(bqkv_g + l*384 + sel*128 + h*32 + (ft & 1)*16 + q*4);
#pragma unroll
            for (int r = 0; r < 4; ++r) v[r] += bq[r];
            if (sel == 0){
#pragma unroll
              for (int r = 0; r < 4; ++r) v[r] *= 0.17677669529663687f;
              store_packed_b64(Qh, 1, ts, ft, v, q, c);
            } else if (sel == 1){
              store_packed_b64(Kh, 1, ts, ft - 2, v, q, c);
            } else {
              int td = ft - 4;
              int qp = ((ts & 1) << 1) + (c >> 3);
              hf* pb = VTh + ((td*4 + (ts >> 1)) << 9) + (c & 7);
#pragma unroll
              for (int r = 0; r < 4; ++r) pb[(qp*16 + q*4 + r) << 3] = (hf)v[r];
            }
          }
      }
      __syncthreads();
      // scores + softmax (no max-sub; scores small) + P + AV (wave w owns q-tile w)
      {
        hf8 qf = *(const hf8*)(Qh + (w << 9) + lane*8);
        f4 sc[8];
#pragma unroll
        for (int kst = 0; kst < 8; ++kst){
          hf8 kv = *(const hf8*)(Kh + (kst << 9) + lane*8);
          f4 z = {0.f,0.f,0.f,0.f};
          sc[kst] = __builtin_amdgcn_mfma_f32_16x16x32_f16(kv, qf, z, 0, 0, 0);
        }
        float ls = 0.f;
#pragma unroll
        for (int kst = 0; kst < 8; ++kst)
#pragma unroll
          for (int r = 0; r < 4; ++r){
            float e = __expf(sc[kst][r]);
            sc[kst][r] = e; ls += e;
          }
        ls += __shfl_xor(ls, 16);
        ls += __shfl_xor(ls, 32);
        float rl = 1.f / ls;
        hf* Pw = Ph + (w << 9);
#pragma unroll
        for (int ks = 0; ks < 4; ++ks){
#pragma unroll
          for (int h2 = 0; h2 < 2; ++h2){
            int kst = 2*ks + h2;
            int qp = h2*2 + (q >> 1);
            int j0 = (q & 1) << 2;
            hf4 pv;
#pragma unroll
            for (int r = 0; r < 4; ++r) pv[r] = (hf)(sc[kst][r] * rl);
            *(hf4*)(Pw + qp*128 + c*8 + j0) = pv;
          }
          hf8 bp = *(const hf8*)(Pw + lane*8);
          hf8 a0 = *(const hf8*)(VTh + ((     ks) << 9) + lane*8);
          hf8 a1 = *(const hf8*)(VTh + ((4 +  ks) << 9) + lane*8);
          oacc[2*h]     = __builtin_amdgcn_mfma_f32_16x16x32_f16(a0, bp, oacc[2*h],     0, 0, 0);
          oacc[2*h + 1] = __builtin_amdgcn_mfma_f32_16x16x32_f16(a1, bp, oacc[2*h + 1], 0, 0, 0);
        }
      }
    } // heads

    // prefetch WO A fragments before the OB barriers
    hf8 awo[2][4];
    loadA2<4>(awo, wsp + WSH_WO + l*16384, npair, lane);
    __syncthreads();
#pragma unroll
    for (int ft = 0; ft < 8; ++ft) store_packed_b64(SCh, 4, w, ft, oacc[ft], q, c);
    __syncthreads();

    // WO projection
    {
      f4 acc[4][2];
#pragma unroll
      for (int i = 0; i < 4; ++i)
#pragma unroll
        for (int j = 0; j < 2; ++j){ f4 z = {0.f,0.f,0.f,0.f}; acc[i][j] = z; }
      gemmBpre<4>(acc, awo, SCh, shalf, lane);
      __syncthreads();
      f4 bo0 = *(const f4*)(bo_g + l*128 + (2*npair    )*16 + q*4);
      f4 bo1 = *(const f4*)(bo_g + l*128 + (2*npair + 1)*16 + q*4);
#pragma unroll
      for (int si = 0; si < 4; ++si)
#pragma unroll
        for (int jn = 0; jn < 2; ++jn){
          f4 v = acc[si][jn];
          f4 bo = jn ? bo1 : bo0;
#pragma unroll
          for (int r = 0; r < 4; ++r) v[r] += bo[r];
          store_packed_b64(SCh, 4, shalf*4 + si, 2*npair + jn, v, q, c);
        }
    }
    __syncthreads();
    ln_pass(ACTh, SCh, ln1g_g + l*128, ln1b_g + l*128, t);

    // FFN with A prefetch pipelined across barriers
    {
      f4 facc[4][2];
#pragma unroll
      for (int i = 0; i < 4; ++i)
#pragma unroll
        for (int j = 0; j < 2; ++j){ f4 z = {0.f,0.f,0.f,0.f}; facc[i][j] = z; }
      hf8 af1[2][4], af2[2][4];
      loadA2<4>(af1, wsp + WSH_FW1 + (l*2 + 0)*16384, npair, lane);
      __syncthreads();   // ln_pass done
      // ch0 FFN1
      {
        f4 acc[4][2];
#pragma unroll
        for (int i = 0; i < 4; ++i)
#pragma unroll
          for (int j = 0; j < 2; ++j){ f4 z = {0.f,0.f,0.f,0.f}; acc[i][j] = z; }
        gemmBpre<4>(acc, af1, ACTh, shalf, lane);
        f4 fb0 = *(const f4*)(fb1_g + l*256 + (2*npair    )*16 + q*4);
        f4 fb1v = *(const f4*)(fb1_g + l*256 + (2*npair + 1)*16 + q*4);
#pragma unroll
        for (int si = 0; si < 4; ++si)
#pragma unroll
          for (int jn = 0; jn < 2; ++jn){
            f4 v = acc[si][jn];
            f4 fb = jn ? fb1v : fb0;
#pragma unroll
            for (int r = 0; r < 4; ++r) v[r] = fmaxf(v[r] + fb[r], 0.f);
            store_packed_b64(SCh, 4, shalf*4 + si, 2*npair + jn, v, q, c);
          }
      }
      loadA2<4>(af2, wsp + WSH_FW2 + (l*2 + 0)*16384, npair, lane);
      __syncthreads();
      gemmBpre<4>(facc, af2, SCh, shalf, lane);
      loadA2<4>(af1, wsp + WSH_FW1 + (l*2 + 1)*16384, npair, lane);
      __syncthreads();
      // ch1 FFN1
      {
        f4 acc[4][2];
#pragma unroll
        for (int i = 0; i < 4; ++i)
#pragma unroll
          for (int j = 0; j < 2; ++j){ f4 z = {0.f,0.f,0.f,0.f}; acc[i][j] = z; }
        gemmBpre<4>(acc, af1, ACTh, shalf, lane);
        f4 fb0 = *(const f4*)(fb1_g + l*256 + 128 + (2*npair    )*16 + q*4);
        f4 fb1v = *(const f4*)(fb1_g + l*256 + 128 + (2*npair + 1)*16 + q*4);
#pragma unroll
        for (int si = 0; si < 4; ++si)
#pragma unroll
          for (int jn = 0; jn < 2; ++jn){
            f4 v = acc[si][jn];
            f4 fb = jn ? fb1v : fb0;
#pragma unroll
            for (int r = 0; r < 4; ++r) v[r] = fmaxf(v[r] + fb[r], 0.f);
            store_packed_b64(SCh, 4, shalf*4 + si, 2*npair + jn, v, q, c);
          }
      }
      loadA2<4>(af2, wsp + WSH_FW2 + (l*2 + 1)*16384, npair, lane);
      __syncthreads();
      gemmBpre<4>(facc, af2, SCh, shalf, lane);
      __syncthreads();
      f4 f20 = *(const f4*)(fb2_g + l*128 + (2*npair    )*16 + q*4);
      f4 f21 = *(const f4*)(fb2_g + l*128 + (2*npair + 1)*16 + q*4);
#pragma unroll
      for (int si = 0; si < 4; ++si)
#pragma unroll
        for (int jn = 0; jn < 2; ++jn){
          f4 v = facc[si][jn];
          f4 fb = jn ? f21 : f20;
#pragma unroll
          for (int r = 0; r < 4; ++r) v[r] += fb[r];
          store_packed_b64(SCh, 4, shalf*4 + si, 2*npair + jn, v, q, c);
        }
    }
    __syncthreads();
    ln_pass(ACTh, SCh, ln2g_g + l*128, ln2b_g + l*128, t);
    __syncthreads();
  } // layers

  // ===== cond_emb mean over s -> cemb[b] (global) =====
  {
    int o = t & 15;
    float fs[8];
#pragma unroll
    for (int j = 0; j < 8; ++j) fs[j] = 0.f;
#pragma unroll
    for (int u = 0; u < 4; ++u){
      int s = (t >> 4)*4 + u;
      hf8 v = *(const hf8*)(ACTh + (((s >> 4)*4 + (o >> 2)) << 9) + (((o & 3)*16 + (s & 15)) << 3));
#pragma unroll
      for (int j = 0; j < 8; ++j) fs[j] += (float)v[j];
    }
#pragma unroll
    for (int j = 0; j < 8; ++j){
      fs[j] += __shfl_xor(fs[j], 16);
      fs[j] += __shfl_xor(fs[j], 32);
    }
    if (lane < 16){
      f4 v0, v1;
#pragma unroll
      for (int j = 0; j < 4; ++j){ v0[j] = fs[j]; v1[j] = fs[j+4]; }
      *(f4*)(SCf + w*128 + o*8)     = v0;
      *(f4*)(SCf + w*128 + o*8 + 4) = v1;
    }
  }
  __syncthreads();
  if (t < 128){
    float a = 0.f;
#pragma unroll
    for (int wv = 0; wv < 8; ++wv) a += SCf[wv*128 + t];
    cemb[b*128 + t] = a * (1.f/128.f);
  }
}

// ---------------- tail kernel: one block per batch, 256 threads ----------------
__global__ __launch_bounds__(256, 8) void tail_k(
    const float* __restrict__ x, const int* __restrict__ tstep, const float* __restrict__ cemb,
    const float* __restrict__ t_b1, const float* __restrict__ t_b2,
    const float* __restrict__ mw_b1,
    const float* __restrict__ mw_w2, const float* __restrict__ mw_b2,
    const float* __restrict__ s_w1, const float* __restrict__ s_b1,
    const float* __restrict__ s_w2, const float* __restrict__ s_b2,
    const hf* __restrict__ sp1, float* __restrict__ out)
{
  __shared__ float sw01[1024], sw2[1024];
  __shared__ float cvec[512];
  __shared__ float scr[1024];
  __shared__ float mwh[128], mwls[4];
  __shared__ hf te_h[128], th_h[256], comb_h[256];
  const int b = blockIdx.x;
  const int t = threadIdx.x;

  for (int i = t; i < 1024; i += 256){
    int row = i >> 9, k = (i >> 7) & 3, j = i & 127;
    sw01[i] = s_w1[k*33024 + row*128 + j];
    sw2[i]  = s_w2[i];
  }
  if (t < 128){
    int i = t & 63;
    float f = __expf(-logf(10000.f) * (float)i * (1.f/64.f));
    float a = (float)tstep[b] * f;
    te_h[t] = (hf)((t < 64) ? cosf(a) : sinf(a));
    comb_h[128 + t] = (hf)cemb[b*128 + t];
  }
  __syncthreads();

  {
    const hf* tp1 = sp1 + TPH_TW1;
    float a = t_b1[t];
#pragma unroll 8
    for (int ii = 0; ii < 64; ++ii){
      hf2 wp = *(const hf2*)(tp1 + ii*512 + 2*t);
      hf2 tp = *(const hf2*)(te_h + 2*ii);
      a = fdot2f(tp, wp, a);
    }
    th_h[t] = (hf)dsilu(a);
  }
  __syncthreads();

  {
    const hf* tp2 = sp1 + TPH_TW2;
    int ih = t >> 7, j = t & 127;
    float a = ih ? 0.f : t_b2[j];
#pragma unroll 8
    for (int ii = 0; ii < 64; ++ii){
      hf2 wp = *(const hf2*)(tp2 + (ih*64 + ii)*256 + 2*j);
      hf2 tp = *(const hf2*)(th_h + ih*128 + 2*ii);
      a = fdot2f(tp, wp, a);
    }
    scr[t] = a;
  }
  __syncthreads();
  if (t < 128) comb_h[t] = (hf)(scr[t] + scr[128 + t]);
  __syncthreads();

  {
    const hf* swp = sp1 + TPH_SW1;
    int ih = t >> 7, k = (t >> 5) & 3, j4 = t & 31;
    f4 a = {0.f, 0.f, 0.f, 0.f};
    const hf* wp = swp + ((k*128 + ih*64)*128 + j4*4)*2;
#pragma unroll 4
    for (int ii = 0; ii < 64; ++ii){
      hf8 wv = *(const hf8*)(wp + ii*256);
      hf2 cb = *(const hf2*)(comb_h + ih*128 + 2*ii);
      hf2 w01; w01[0] = wv[0]; w01[1] = wv[1];
      hf2 w23; w23[0] = wv[2]; w23[1] = wv[3];
      hf2 w45; w45[0] = wv[4]; w45[1] = wv[5];
      hf2 w67; w67[0] = wv[6]; w67[1] = wv[7];
      a[0] = fdot2f(cb, w01, a[0]);
      a[1] = fdot2f(cb, w23, a[1]);
      a[2] = fdot2f(cb, w45, a[2]);
      a[3] = fdot2f(cb, w67, a[3]);
    }
    ((f4*)scr)[ih*128 + k*32 + j4] = a;
  }
  __syncthreads();

  if (t < 128){
    f4 r0 = ((f4*)scr)[t];
    f4 r1 = ((f4*)scr)[128 + t];
    int k = t >> 5, j4 = t & 31;
    f4 sb = *(const f4*)(s_b1 + k*128 + j4*4);
    f4 r; r[0] = r0[0]+r1[0]+sb[0]; r[1] = r0[1]+r1[1]+sb[1];
    r[2] = r0[2]+r1[2]+sb[2]; r[3] = r0[3]+r1[3]+sb[3];
    ((f4*)cvec)[t] = r;
  } else {
    const hf* mp1 = sp1 + TPH_MW1;
    int j = t - 128;
    float a = mw_b1[j];
#pragma unroll 8
    for (int ii = 0; ii < 128; ++ii){
      hf2 wp = *(const hf2*)(mp1 + ii*256 + 2*j);
      hf2 cp = *(const hf2*)(comb_h + 2*ii);
      a = fdot2f(cp, wp, a);
    }
    mwh[j] = dsilu(a);
  }
  __syncthreads();

  if (t < 64){
    int cc = t & 3, j0 = t >> 2;
    float a = 0.f;
#pragma unroll
    for (int i = 0; i < 8; ++i){
      int j = j0 + 16*i;
      a += mwh[j] * mw_w2[j*4 + cc];
    }
    a += __shfl_xor(a, 4);
    a += __shfl_xor(a, 8);
    a += __shfl_xor(a, 16);
    a += __shfl_xor(a, 32);
    if (t < 4) mwls[t] = a + mw_b2[t];
  }
#pragma unroll
  for (int u = 0; u < 2; ++u){
    int o = t + u*256, k = o >> 7, s = o & 127;
    float x0 = x[b*256 + s];
    float x1 = x[b*256 + 128 + s];
    float a0 = 0.f, a1 = 0.f;
    const f4* cvp = (const f4*)cvec + k*32;
    const f4* w0p = (const f4*)sw01 + k*32;
    const f4* w1p = (const f4*)sw01 + 128 + k*32;
    const f4* s2p = (const f4*)sw2 + k*64;
#pragma unroll 2
    for (int j4 = 0; j4 < 32; ++j4){
      f4 cv = cvp[j4], w0 = w0p[j4], w1 = w1p[j4];
      f4 s20 = s2p[2*j4], s21 = s2p[2*j4 + 1];
      float h0 = dtanh(cv[0] + x0*w0[0] + x1*w1[0]);
      float h1 = dtanh(cv[1] + x0*w0[1] + x1*w1[1]);
      float h2 = dtanh(cv[2] + x0*w0[2] + x1*w1[2]);
      float h3 = dtanh(cv[3] + x0*w0[3] + x1*w1[3]);
      a0 += h0*s20[0] + h1*s20[2] + h2*s21[0] + h3*s21[2];
      a1 += h0*s20[1] + h1*s20[3] + h2*s21[1] + h3*s21[3];
    }
    scr[k*256 + s]       = a0 + s_b2[2*k];
    scr[k*256 + 128 + s] = a1 + s_b2[2*k + 1];
  }
  __syncthreads();

  {
    int row = t >> 7, s = t & 127;
    float l0 = mwls[0], l1 = mwls[1], l2 = mwls[2], l3 = mwls[3];
    float mx = fmaxf(fmaxf(l0, l1), fmaxf(l2, l3));
    float e0 = __expf(l0 - mx), e1 = __expf(l1 - mx), e2 = __expf(l2 - mx), e3 = __expf(l3 - mx);
    float rs = 1.f / (e0 + e1 + e2 + e3);
    float a = e0*scr[0*256 + row*128 + s] + e1*scr[1*256 + row*128 + s]
            + e2*scr[2*256 + row*128 + s] + e3*scr[3*256 + row*128 + s];
    out[b*256 + row*128 + s] = a * rs;
  }
}

extern "C" void kernel_launch(void* const* d_in, const int* in_sizes, int n_in,
                              void* d_out, int out_size, void* d_ws, size_t ws_size,
                              hipStream_t stream){
  (void)n_in; (void)ws_size; (void)out_size;
  hipFuncSetAttribute((const void*)fused_fp, hipFuncAttributeMaxDynamicSharedMemorySize, SMEM_BYTES);
  int B = in_sizes[1];
  hf* wsp = (hf*)d_ws;
  float* cemb = (float*)((char*)d_ws + CEMB_BYTE_OFF);
  hf* sp1 = (hf*)((char*)d_ws + SP1_BYTE_OFF);
  prep_all<<<dim3((WSH_TOTAL + TPH_TOTAL + 255) / 256), dim3(256), 0, stream>>>(
      (const float*)d_in[11], (const float*)d_in[13], (const float*)d_in[17],
      (const float*)d_in[19], (const float*)d_in[9],
      (const float*)d_in[27], (const float*)d_in[3], (const float*)d_in[5],
      (const float*)d_in[23], wsp, sp1);
  fused_fp<<<dim3(B), dim3(NTH), SMEM_BYTES, stream>>>(
      (const float*)d_in[2],
      (const float*)d_in[7], (const float*)d_in[8], (const float*)d_in[10],
      (const float*)d_in[12], (const float*)d_in[14],
      (const float*)d_in[15], (const float*)d_in[16],
      (const float*)d_in[18], (const float*)d_in[20],
      (const float*)d_in[21], (const float*)d_in[22],
      wsp, cemb);
  tail_k<<<dim3(B), dim3(256), 0, stream>>>(
      (const float*)d_in[0], (const int*)d_in[1], cemb,
      (const float*)d_in[4], (const float*)d_in[6],
      (const float*)d_in[24],
      (const float*)d_in[25], (const float*)d_in[26],
      (const float*)d_in[27], (const float*)d_in[28], (const float*)d_in[29], (const float*)d_in[30],
      sp1, (float*)d_out);
}